// Round 7
// baseline (163.167 us; speedup 1.0000x reference)
//
#include <hip/hip_runtime.h>

// Log-signature depth 3, d=8, L=256, B=2048 — single fused kernel.
// One block (4 waves) per batch element; wave w scans chunk [64w,64w+64)
// from zero state (dx row t=255 zeroed = Chen identity step); wave 0 folds
// chunks left-to-right: C1=A1+B1; C2=A2+B2+A1⊗B1; C3=A3+B3+A1⊗B2+A2⊗B1.
// Lane l=(i=l>>3, j=l&7): h1=0.5*S1[i], s2=S2[i][j], s3[k]=S3[i][j][k].
// Step (old state on RHS):
//   S3[k] += (S2 + (0.5*S1[i] + dx[i]/6)*dx[j]) * dx[k]
//   S2    += (S1[i] + 0.5*dx[i]) * dx[j];   S1[i] += dx[i]
//
// R1/R3 established the hot loop is LDS-return-BW-bound (~36 cyc/step/wave:
// 2x b128 f32 row + 2x b32). Fix: bf16 in the hot loop halves LDS bytes:
//  - rowsB[t]: 8 bf16 = 16 B -> ONE ds_read_b128 per step (was two),
//    wave-wide same-address broadcast; 8 shift/and unpacks (VALU has slack).
//  - dxT bf16 transposed [c][t], ushort stride 264 (528 B): one b128 = 8
//    steps of dxi. Rows start at bank 4i, read covers banks 4i..4i+3 ->
//    disjoint across the 8 addresses, 8-way same-address broadcast (free).
// R6 BUG FIXED HERE: a uint4 is 8 bf16 = 8 steps, so the macro-group is 8
// steps (R6 indexed 4 uints past the vector for steps 8..15).
// LDS ~15 cyc/step/wave -> ~13 us floor at 32 waves/CU; VALU ~23 instr/step
// (~10 us, hidden). bf16 truncation of dx: rel 2^-7 -> absmax ~0.05 << 0.485.

#define LEN 256
#define DCH 8
#define NW 4
#define CHUNK 64
#define TPADB 264     // ushort stride: 528 B per channel row; 16B-aligned reads
#define OUTSTRIDE (DCH + DCH*DCH + DCH*DCH*DCH)  // 584

__device__ __forceinline__ float lo16(unsigned int u) {
    return __uint_as_float(u << 16);
}
__device__ __forceinline__ float hi16(unsigned int u) {
    return __uint_as_float(u & 0xffff0000u);
}

__global__ __launch_bounds__(256, 8) void logsig_fused(const float* __restrict__ x,
                                                       float* __restrict__ out) {
    __shared__ __align__(16) unsigned short dxT[DCH][TPADB];  // bf16 transposed
    __shared__ __align__(16) unsigned int   rowsB[LEN * 4];   // packed bf16 rows
    __shared__ __align__(16) float sig1[NW - 1][8];
    __shared__ __align__(16) float sig2[NW - 1][64];
    __shared__ __align__(16) float sig3[NW - 1][512];
    __shared__ __align__(16) float s1buf[8];
    __shared__ __align__(16) float s2buf[64];

    const int tid  = threadIdx.x;
    const int w    = tid >> 6;
    const int lane = tid & 63;
    const int i    = lane >> 3;
    const int j    = lane & 7;
    const int b    = blockIdx.x;

    // ---- Stage dx as bf16 (truncation) into rowsB (natural) + dxT (transposed) ----
    const float4* x4 = (const float4*)(x + (size_t)b * (LEN * DCH));
    for (int f = tid; f < 512; f += 256) {     // f = float4 index of dx
        float4 dv;
        if (f < 510) {
            float4 a = x4[f];
            float4 c = x4[f + 2];
            dv.x = c.x - a.x; dv.y = c.y - a.y; dv.z = c.z - a.z; dv.w = c.w - a.w;
        } else {
            dv.x = 0.f; dv.y = 0.f; dv.z = 0.f; dv.w = 0.f;   // zero row t=255
        }
        const int t  = f >> 1;
        const int c0 = (f & 1) * 4;
        const unsigned int ux = __float_as_uint(dv.x), uy = __float_as_uint(dv.y);
        const unsigned int uz = __float_as_uint(dv.z), uw4 = __float_as_uint(dv.w);
        rowsB[t * 4 + (f & 1) * 2 + 0] = (ux >> 16) | (uy & 0xffff0000u);
        rowsB[t * 4 + (f & 1) * 2 + 1] = (uz >> 16) | (uw4 & 0xffff0000u);
        dxT[c0 + 0][t] = (unsigned short)(ux >> 16);
        dxT[c0 + 1][t] = (unsigned short)(uy >> 16);
        dxT[c0 + 2][t] = (unsigned short)(uz >> 16);
        dxT[c0 + 3][t] = (unsigned short)(uw4 >> 16);
    }
    __syncthreads();

    // ---- Chunk scan: 64 steps per wave, 8-step macro groups ----
    float h1 = 0.f, s2 = 0.f;
    float s3[8];
#pragma unroll
    for (int k = 0; k < 8; ++k) s3[k] = 0.f;

    const float c6 = 1.f / 6.f;
    const int tb0 = w * CHUNK;
    const unsigned short* vip = &dxT[i][tb0];
    const unsigned short* vjp = &dxT[j][tb0];

    for (int g = 0; g < 8; ++g) {              // 8 steps per group
        uint4 vi8 = *(const uint4*)(vip + g * 8);   // dxi for 8 steps (8 bf16)
        uint4 vj8 = *(const uint4*)(vjp + g * 8);   // dxj for 8 steps
        const unsigned int* rp = &rowsB[(tb0 + g * 8) * 4];
#pragma unroll
        for (int u = 0; u < 8; ++u) {
            uint4 R = *(const uint4*)(rp + u * 4);  // row t: 8 bf16, bcast b128
            unsigned int dvi = ((const unsigned int*)&vi8)[u >> 1];
            unsigned int dvj = ((const unsigned int*)&vj8)[u >> 1];
            float dxi = (u & 1) ? hi16(dvi) : lo16(dvi);
            float dxj = (u & 1) ? hi16(dvj) : lo16(dvj);
            float h1n = fmaf(0.5f, dxi, h1);   // 0.5*(S1+dxi)
            float uu  = h1 + h1n;              // S1 + 0.5*dxi
            float tt  = fmaf(c6, dxi, h1);     // 0.5*S1 + dxi/6
            float w3  = fmaf(tt, dxj, s2);
            s3[0] = fmaf(w3, lo16(R.x), s3[0]);
            s3[1] = fmaf(w3, hi16(R.x), s3[1]);
            s3[2] = fmaf(w3, lo16(R.y), s3[2]);
            s3[3] = fmaf(w3, hi16(R.y), s3[3]);
            s3[4] = fmaf(w3, lo16(R.z), s3[4]);
            s3[5] = fmaf(w3, hi16(R.z), s3[5]);
            s3[6] = fmaf(w3, lo16(R.w), s3[6]);
            s3[7] = fmaf(w3, hi16(R.w), s3[7]);
            s2 = fmaf(uu, dxj, s2);
            h1 = h1n;
        }
    }

    float s1 = h1 + h1;   // S1[i]

    // ---- Publish chunk signatures (waves 1..3) ----
    if (w != 0) {
        if (j == 0) sig1[w - 1][i] = s1;
        sig2[w - 1][lane] = s2;
        float* sp = &sig3[w - 1][lane * 8];
        *(float4*)(sp)     = make_float4(s3[0], s3[1], s3[2], s3[3]);
        *(float4*)(sp + 4) = make_float4(s3[4], s3[5], s3[6], s3[7]);
    }
    __syncthreads();

    if (w != 0) return;

    // ---- Fold chunks 1..3 into wave 0's registers (A=accum, B=chunk c) ----
    for (int c = 0; c < NW - 1; ++c) {
        float B1i  = sig1[c][i];
        float B1j  = sig1[c][j];
        float B2ij = sig2[c][lane];
        float4 b1a = *(const float4*)&sig1[c][0];
        float4 b1b = *(const float4*)&sig1[c][4];
        const float* b2row = &sig2[c][j * 8];
        float4 b2a = *(const float4*)(b2row);
        float4 b2b = *(const float4*)(b2row + 4);
        const float* b3row = &sig3[c][lane * 8];
        float4 b3a = *(const float4*)(b3row);
        float4 b3b = *(const float4*)(b3row + 4);
        float B1k[8]  = {b1a.x, b1a.y, b1a.z, b1a.w, b1b.x, b1b.y, b1b.z, b1b.w};
        float B2jk[8] = {b2a.x, b2a.y, b2a.z, b2a.w, b2b.x, b2b.y, b2b.z, b2b.w};
        float B3[8]   = {b3a.x, b3a.y, b3a.z, b3a.w, b3b.x, b3b.y, b3b.z, b3b.w};
#pragma unroll
        for (int k = 0; k < 8; ++k)   // uses OLD s1 (A1), OLD s2 (A2)
            s3[k] = s3[k] + B3[k] + s1 * B2jk[k] + s2 * B1k[k];
        s2 = s2 + B2ij + s1 * B1j;    // uses OLD s1
        s1 = s1 + B1i;
    }

    // ---- Log map epilogue (wave-internal LDS exchange) ----
    if (j == 0) s1buf[i] = s1;
    s2buf[lane] = s2;

    float S1r[8], S2rj[8];
#pragma unroll
    for (int k = 0; k < 8; ++k) S1r[k] = s1buf[k];
#pragma unroll
    for (int k = 0; k < 8; ++k) S2rj[k] = s2buf[j * 8 + k];
    float s1j = s1buf[j];

    float* ob = out + (size_t)b * OUTSTRIDE;
    if (lane < 8) ob[lane] = s1buf[lane];            // l1
    ob[8 + lane] = fmaf(-0.5f * s1, s1j, s2);        // l2

    float c3 = (1.f / 3.f) * s1 * s1j;
    float l3[8];
#pragma unroll
    for (int k = 0; k < 8; ++k)
        l3[k] = s3[k] - 0.5f * (s1 * S2rj[k] + s2 * S1r[k]) + c3 * S1r[k];
    float* p3 = ob + 72 + lane * 8;
    *(float4*)(p3)     = make_float4(l3[0], l3[1], l3[2], l3[3]);
    *(float4*)(p3 + 4) = make_float4(l3[4], l3[5], l3[6], l3[7]);
}

extern "C" void kernel_launch(void* const* d_in, const int* in_sizes, int n_in,
                              void* d_out, int out_size, void* d_ws, size_t ws_size,
                              hipStream_t stream) {
    const float* x = (const float*)d_in[0];
    float* out = (float*)d_out;
    const int B = in_sizes[0] / (LEN * DCH);   // 2048
    hipLaunchKernelGGL(logsig_fused, dim3(B), dim3(256), 0, stream, x, out);
}

// Round 8
// 79.154 us; speedup vs baseline: 2.0614x; 2.0614x over previous
//
#include <hip/hip_runtime.h>

// Log-signature depth 3, d=8, L=256, B=2048 — single fused kernel.
// One block (4 waves) per batch element; wave w scans chunk [64w,64w+64)
// from zero state (dx row t=255 zeroed = Chen identity step); wave 0 folds
// chunks left-to-right: C1=A1+B1; C2=A2+B2+A1⊗B1; C3=A3+B3+A1⊗B2+A2⊗B1.
// Lane l=(i=l>>3, j=l&7): h1=0.5*S1[i], s2=S2[i][j], s3[k]=S3[i][j][k].
// Step (old state on RHS):
//   S3[k] += (S2 + (0.5*S1[i] + dx[i]/6)*dx[j]) * dx[k]
//   S2    += (S1[i] + 0.5*dx[i]) * dx[j];   S1[i] += dx[i]
//
// R1/R3: hot loop is LDS-return-BW-bound (~36 cyc/step/wave f32). bf16
// halves LDS bytes: rowsB[t] = 8 bf16 = ONE b128/step (broadcast);
// dxT bf16 transposed (ushort stride 264) = one b128 per 8 steps for dxi.
// R7 LESSON: __launch_bounds__(256,8) forced VGPR=32 -> 320 MB scratch
// spill traffic, 110 us dispatches. Use plain __launch_bounds__(256) and
// let the allocator pick (~72 VGPR still gives 8 waves/SIMD naturally).
// bf16 staging uses round-to-nearest-even (truncation biased the scan:
// absmax 0.25; RNE should give ~0.1).

#define LEN 256
#define DCH 8
#define NW 4
#define CHUNK 64
#define TPADB 264     // ushort stride: 528 B per channel row; 16B-aligned reads
#define OUTSTRIDE (DCH + DCH*DCH + DCH*DCH*DCH)  // 584

__device__ __forceinline__ float lo16(unsigned int u) {
    return __uint_as_float(u << 16);
}
__device__ __forceinline__ float hi16(unsigned int u) {
    return __uint_as_float(u & 0xffff0000u);
}
__device__ __forceinline__ unsigned int rne_bf16(float v) {   // -> low 16 bits
    unsigned int u = __float_as_uint(v);
    return (u + 0x7fffu + ((u >> 16) & 1u)) >> 16;
}

__global__ __launch_bounds__(256) void logsig_fused(const float* __restrict__ x,
                                                    float* __restrict__ out) {
    __shared__ __align__(16) unsigned short dxT[DCH][TPADB];  // bf16 transposed
    __shared__ __align__(16) unsigned int   rowsB[LEN * 4];   // packed bf16 rows
    __shared__ __align__(16) float sig1[NW - 1][8];
    __shared__ __align__(16) float sig2[NW - 1][64];
    __shared__ __align__(16) float sig3[NW - 1][512];
    __shared__ __align__(16) float s1buf[8];
    __shared__ __align__(16) float s2buf[64];

    const int tid  = threadIdx.x;
    const int w    = tid >> 6;
    const int lane = tid & 63;
    const int i    = lane >> 3;
    const int j    = lane & 7;
    const int b    = blockIdx.x;

    // ---- Stage dx as bf16 (RNE) into rowsB (natural) + dxT (transposed) ----
    const float4* x4 = (const float4*)(x + (size_t)b * (LEN * DCH));
    for (int f = tid; f < 512; f += 256) {     // f = float4 index of dx
        float4 dv;
        if (f < 510) {
            float4 a = x4[f];
            float4 c = x4[f + 2];
            dv.x = c.x - a.x; dv.y = c.y - a.y; dv.z = c.z - a.z; dv.w = c.w - a.w;
        } else {
            dv.x = 0.f; dv.y = 0.f; dv.z = 0.f; dv.w = 0.f;   // zero row t=255
        }
        const int t  = f >> 1;
        const int c0 = (f & 1) * 4;
        const unsigned int bx = rne_bf16(dv.x), by = rne_bf16(dv.y);
        const unsigned int bz = rne_bf16(dv.z), bw = rne_bf16(dv.w);
        rowsB[t * 4 + (f & 1) * 2 + 0] = bx | (by << 16);
        rowsB[t * 4 + (f & 1) * 2 + 1] = bz | (bw << 16);
        dxT[c0 + 0][t] = (unsigned short)bx;
        dxT[c0 + 1][t] = (unsigned short)by;
        dxT[c0 + 2][t] = (unsigned short)bz;
        dxT[c0 + 3][t] = (unsigned short)bw;
    }
    __syncthreads();

    // ---- Chunk scan: 64 steps per wave, 8-step macro groups ----
    float h1 = 0.f, s2 = 0.f;
    float s3[8];
#pragma unroll
    for (int k = 0; k < 8; ++k) s3[k] = 0.f;

    const float c6 = 1.f / 6.f;
    const int tb0 = w * CHUNK;
    const unsigned short* vip = &dxT[i][tb0];
    const unsigned short* vjp = &dxT[j][tb0];

    for (int g = 0; g < 8; ++g) {              // 8 steps per group
        uint4 vi8 = *(const uint4*)(vip + g * 8);   // dxi for 8 steps (8 bf16)
        uint4 vj8 = *(const uint4*)(vjp + g * 8);   // dxj for 8 steps
        const unsigned int* rp = &rowsB[(tb0 + g * 8) * 4];
#pragma unroll
        for (int u = 0; u < 8; ++u) {
            uint4 R = *(const uint4*)(rp + u * 4);  // row t: 8 bf16, bcast b128
            unsigned int dvi = ((const unsigned int*)&vi8)[u >> 1];
            unsigned int dvj = ((const unsigned int*)&vj8)[u >> 1];
            float dxi = (u & 1) ? hi16(dvi) : lo16(dvi);
            float dxj = (u & 1) ? hi16(dvj) : lo16(dvj);
            float h1n = fmaf(0.5f, dxi, h1);   // 0.5*(S1+dxi)
            float uu  = h1 + h1n;              // S1 + 0.5*dxi
            float tt  = fmaf(c6, dxi, h1);     // 0.5*S1 + dxi/6
            float w3  = fmaf(tt, dxj, s2);
            s3[0] = fmaf(w3, lo16(R.x), s3[0]);
            s3[1] = fmaf(w3, hi16(R.x), s3[1]);
            s3[2] = fmaf(w3, lo16(R.y), s3[2]);
            s3[3] = fmaf(w3, hi16(R.y), s3[3]);
            s3[4] = fmaf(w3, lo16(R.z), s3[4]);
            s3[5] = fmaf(w3, hi16(R.z), s3[5]);
            s3[6] = fmaf(w3, lo16(R.w), s3[6]);
            s3[7] = fmaf(w3, hi16(R.w), s3[7]);
            s2 = fmaf(uu, dxj, s2);
            h1 = h1n;
        }
    }

    float s1 = h1 + h1;   // S1[i]

    // ---- Publish chunk signatures (waves 1..3) ----
    if (w != 0) {
        if (j == 0) sig1[w - 1][i] = s1;
        sig2[w - 1][lane] = s2;
        float* sp = &sig3[w - 1][lane * 8];
        *(float4*)(sp)     = make_float4(s3[0], s3[1], s3[2], s3[3]);
        *(float4*)(sp + 4) = make_float4(s3[4], s3[5], s3[6], s3[7]);
    }
    __syncthreads();

    if (w != 0) return;

    // ---- Fold chunks 1..3 into wave 0's registers (A=accum, B=chunk c) ----
    for (int c = 0; c < NW - 1; ++c) {
        float B1i  = sig1[c][i];
        float B1j  = sig1[c][j];
        float B2ij = sig2[c][lane];
        float4 b1a = *(const float4*)&sig1[c][0];
        float4 b1b = *(const float4*)&sig1[c][4];
        const float* b2row = &sig2[c][j * 8];
        float4 b2a = *(const float4*)(b2row);
        float4 b2b = *(const float4*)(b2row + 4);
        const float* b3row = &sig3[c][lane * 8];
        float4 b3a = *(const float4*)(b3row);
        float4 b3b = *(const float4*)(b3row + 4);
        float B1k[8]  = {b1a.x, b1a.y, b1a.z, b1a.w, b1b.x, b1b.y, b1b.z, b1b.w};
        float B2jk[8] = {b2a.x, b2a.y, b2a.z, b2a.w, b2b.x, b2b.y, b2b.z, b2b.w};
        float B3[8]   = {b3a.x, b3a.y, b3a.z, b3a.w, b3b.x, b3b.y, b3b.z, b3b.w};
#pragma unroll
        for (int k = 0; k < 8; ++k)   // uses OLD s1 (A1), OLD s2 (A2)
            s3[k] = s3[k] + B3[k] + s1 * B2jk[k] + s2 * B1k[k];
        s2 = s2 + B2ij + s1 * B1j;    // uses OLD s1
        s1 = s1 + B1i;
    }

    // ---- Log map epilogue (wave-internal LDS exchange) ----
    if (j == 0) s1buf[i] = s1;
    s2buf[lane] = s2;

    float S1r[8], S2rj[8];
#pragma unroll
    for (int k = 0; k < 8; ++k) S1r[k] = s1buf[k];
#pragma unroll
    for (int k = 0; k < 8; ++k) S2rj[k] = s2buf[j * 8 + k];
    float s1j = s1buf[j];

    float* ob = out + (size_t)b * OUTSTRIDE;
    if (lane < 8) ob[lane] = s1buf[lane];            // l1
    ob[8 + lane] = fmaf(-0.5f * s1, s1j, s2);        // l2

    float c3 = (1.f / 3.f) * s1 * s1j;
    float l3[8];
#pragma unroll
    for (int k = 0; k < 8; ++k)
        l3[k] = s3[k] - 0.5f * (s1 * S2rj[k] + s2 * S1r[k]) + c3 * S1r[k];
    float* p3 = ob + 72 + lane * 8;
    *(float4*)(p3)     = make_float4(l3[0], l3[1], l3[2], l3[3]);
    *(float4*)(p3 + 4) = make_float4(l3[4], l3[5], l3[6], l3[7]);
}

extern "C" void kernel_launch(void* const* d_in, const int* in_sizes, int n_in,
                              void* d_out, int out_size, void* d_ws, size_t ws_size,
                              hipStream_t stream) {
    const float* x = (const float*)d_in[0];
    float* out = (float*)d_out;
    const int B = in_sizes[0] / (LEN * DCH);   // 2048
    hipLaunchKernelGGL(logsig_fused, dim3(B), dim3(256), 0, stream, x, out);
}